// Round 11
// baseline (247.661 us; speedup 1.0000x reference)
//
#include <hip/hip_runtime.h>
#include <math.h>

#define BTOT 16384

typedef __attribute__((ext_vector_type(8))) short s16x8;
typedef __attribute__((ext_vector_type(4))) float f32x4;
typedef __attribute__((ext_vector_type(4))) uint u32x4;
typedef __attribute__((ext_vector_type(2))) float f32x2;
typedef __attribute__((ext_vector_type(2))) uint u32x2;

// U region offsets (in ushorts). Per-node blob: [KTN*512 hi][KTN*512 lo].
#define OFF0 0u          // W0: 128 nodes x 5120
#define OFF1 655360u     // W1: 64 x 8192
#define OFF2 1179648u    // W2: 32 x 8192
#define OFF3 1441792u    // W3: 16 x 8192
#define OFF4 1572864u    // W4: 8 x 8192
#define OFF5 1638400u    // W5: 4 x 8192
#define OFF6 1671168u    // W6: 2 x 8192
#define OFF7 1687552u    // W7: 1 x 8192

__device__ __forceinline__ ushort rtn_bf16(float x) {
  uint u = __builtin_bit_cast(uint, x);
  uint r = u + 0x7fffu + ((u >> 16) & 1u);
  return (ushort)(r >> 16);
}

// ---------------- W-frag prep: all levels -> MFMA B-frag order, bf16 hi/lo ------
__global__ __launch_bounds__(256) void wprep_kernel(
    const float* __restrict__ W0, const float* __restrict__ W1,
    const float* __restrict__ W2, const float* __restrict__ W3,
    const float* __restrict__ W4, const float* __restrict__ W5,
    const float* __restrict__ W6, const float* __restrict__ W7,
    ushort* __restrict__ U) {
  int blk = blockIdx.x;
  const float* Wsrc; ushort* dst; int ktN, din; bool dout1 = false;
  if (blk < 128)      { Wsrc = W0 + blk * 1296;         dst = U + OFF0 + (size_t)blk * 5120;         ktN = 5; din = 9;  }
  else if (blk < 192) { Wsrc = W1 + (blk - 128) * 4096; dst = U + OFF1 + (size_t)(blk - 128) * 8192; ktN = 8; din = 16; }
  else if (blk < 224) { Wsrc = W2 + (blk - 192) * 4096; dst = U + OFF2 + (size_t)(blk - 192) * 8192; ktN = 8; din = 16; }
  else if (blk < 240) { Wsrc = W3 + (blk - 224) * 4096; dst = U + OFF3 + (size_t)(blk - 224) * 8192; ktN = 8; din = 16; }
  else if (blk < 248) { Wsrc = W4 + (blk - 240) * 4096; dst = U + OFF4 + (size_t)(blk - 240) * 8192; ktN = 8; din = 16; }
  else if (blk < 252) { Wsrc = W5 + (blk - 248) * 4096; dst = U + OFF5 + (size_t)(blk - 248) * 8192; ktN = 8; din = 16; }
  else if (blk < 254) { Wsrc = W6 + (blk - 252) * 4096; dst = U + OFF6 + (size_t)(blk - 252) * 8192; ktN = 8; din = 16; }
  else                { Wsrc = W7;                      dst = U + OFF7;                              ktN = 8; din = 16; dout1 = true; }
  int entries = ktN * 512;
  for (int e = threadIdx.x; e < entries; e += 256) {
    int kt = e >> 9, l = (e >> 3) & 63, jv = e & 7;
    int k = kt * 32 + ((l >> 4) << 3) + jv;
    int i = k >> 4, j = k & 15, n = l & 15;
    float w;
    if (dout1) w = (n == 0) ? Wsrc[i * 16 + j] : 0.f;
    else       w = (i < din && j < din) ? Wsrc[(i * din + j) * 16 + n] : 0.f;
    uint u = __builtin_bit_cast(uint, w);
    uint h = u & 0xffff0000u;
    dst[e] = (ushort)(h >> 16);
    dst[entries + e] = rtn_bf16(w - __builtin_bit_cast(float, h));
  }
}

// ---- split + 3 MFMAs for one 16-b tile, given resident wh/wl ------------------
__device__ __forceinline__ f32x4 split3(float li, const f32x2* rf2,
                                        s16x8 wh, s16x8 wl, f32x4 acc) {
  const f32x2 li2 = {li, li};
  u32x4 hv, lv;
#pragma unroll
  for (int jp = 0; jp < 4; ++jp) {
    f32x2 p2 = li2 * rf2[jp];
    u32x2 u2 = __builtin_bit_cast(u32x2, p2);
    u32x2 hb = u2 & 0xffff0000u;
    f32x2 h2 = __builtin_bit_cast(f32x2, hb);
    f32x2 q2 = __builtin_elementwise_fma(li2, rf2[jp], -h2);
    u32x2 uq = __builtin_bit_cast(u32x2, q2);
    hv[jp] = __builtin_amdgcn_perm(u2.y, u2.x, 0x07060302u);
    lv[jp] = __builtin_amdgcn_perm(uq.y, uq.x, 0x07060302u);
  }
  s16x8 ahi = __builtin_bit_cast(s16x8, hv);
  s16x8 alo = __builtin_bit_cast(s16x8, lv);
  acc = __builtin_amdgcn_mfma_f32_16x16x32_bf16(ahi, wh, acc, 0, 0, 0);
  acc = __builtin_amdgcn_mfma_f32_16x16x32_bf16(alo, wh, acc, 0, 0, 0);
  acc = __builtin_amdgcn_mfma_f32_16x16x32_bf16(ahi, wl, acc, 0, 0, 0);
  return acc;
}

// ---------------- single-tile MFMA bilinear core (R7-verified) -----------------
// One wave: C[16 b][16 d] = sum_k A[b,k] W[k,d], A[b, k=i*16+j] = l_i*r_j.
// L0M: 9-dim level-0 inputs, rows >=9 read as zero (PREDICATED, no pad row).
template <int KTN, bool L0M>
__device__ __forceinline__ f32x4 mfma_core(const float* Lcol, const float* Rcol,
                                           const int ld, const ushort* __restrict__ Wf,
                                           int lane) {
  const int g = lane >> 4;
  const int j0 = (g & 1) * 8, gh = g >> 1;
  const float* Lg = Lcol + gh * ld;
  float lf[KTN];
#pragma unroll
  for (int i = 0; i < KTN; ++i)
    lf[i] = (L0M && (2 * i + gh > 8)) ? 0.f : Lg[2 * i * ld];
  f32x2 rf2[4];
#pragma unroll
  for (int j = 0; j < 8; ++j) {
    float v = (L0M && (j0 + j >= 9)) ? 0.f : Rcol[(j0 + j) * ld];
    rf2[j >> 1][j & 1] = v;
  }
  f32x4 acc = {0.f, 0.f, 0.f, 0.f};
  const int entries = KTN * 512;
#pragma unroll
  for (int kt = 0; kt < KTN; ++kt) {
    const s16x8 wh = *(const s16x8*)&Wf[(kt * 64 + lane) * 8];
    const s16x8 wl = *(const s16x8*)&Wf[entries + (kt * 64 + lane) * 8];
    acc = split3(lf[kt], rf2, wh, wl, acc);
  }
  return acc;
}

#define LDW 35   // front leading dim: 35 % 32 = 3 -> <=2-way LDS conflicts (free)

__device__ __forceinline__ void feats_col(float xv, float* Fb, int col) {
  float s1 = __sinf(xv), c1 = __cosf(xv);
  Fb[0 * LDW + col] = 1.f; Fb[1 * LDW + col] = s1; Fb[5 * LDW + col] = c1;
  float sk = s1, ck = c1;
#pragma unroll
  for (int k = 2; k <= 4; ++k) {
    float sn = s1 * ck + c1 * sk, cn = c1 * ck - s1 * sk;
    sk = sn; ck = cn;
    Fb[k * LDW + col] = sk; Fb[(4 + k) * LDW + col] = ck;
  }
}

// ---------------- Levels 0-3 fused, zero-barrier, 128-thr/2-wave blocks --------
// Block = 32 b (wave w owns 16-b subtile). LDS 15.96 KB -> 10 blocks/CU
// (20 waves/CU) with fine block-slot recycling (2-wave skew vs R7's 4-wave).
// No launch_bounds min-waves arg (R6/R8 lesson: tight caps/hoists spill).
__global__ __launch_bounds__(128) void ttn_front_kernel(
    const float* __restrict__ x, const float* __restrict__ fminp,
    const ushort* __restrict__ U, float* __restrict__ s1out) {
  __shared__ float F0[9 * LDW], F1[9 * LDW];
  __shared__ float A0[16 * LDW], B0[16 * LDW];
  __shared__ float A1[16 * LDW], B1[16 * LDW];
  __shared__ float A2[16 * LDW], B2[16 * LDW];

  const int tid = threadIdx.x;
  const int lane = tid & 63, w = tid >> 6;   // w = 0,1
  const int m = lane & 15, g = lane >> 4;
  const int bl = w * 16 + m;
  const int b0 = blockIdx.x * 32;
  const int s = blockIdx.y;
  const float fmin = fminp[0];

  // per-lane x source: lanes<32 handle (b_loc = lane&15, side = lane>>4)
  const float* xw = x + (size_t)(b0 + w * 16 + (lane & 15)) * 256 + s * 16;
  float* outG = s1out + (size_t)(s * 16) * BTOT + b0;

  auto storeL = [&](f32x4 a, float* Out) {
#pragma unroll
    for (int r = 0; r < 4; ++r) Out[m * LDW + w * 16 + g * 4 + r] = a[r];
  };

  for (int t = 0; t < 8; ++t) {
    if (lane < 32) {
      int side = lane >> 4;
      float xv = xw[2 * t + side] * fmin;
      feats_col(xv, side ? F1 : F0, w * 16 + (lane & 15));
    }
    f32x4 a = mfma_core<5, true>(&F0[bl], &F1[bl], LDW,
                                 U + OFF0 + (size_t)(8 * s + t) * 5120, lane);
    storeL(a, (t & 1) ? B0 : A0);
    if (t & 1) {
      f32x4 c1 = mfma_core<8, false>(&A0[bl], &B0[bl], LDW,
                                     U + OFF1 + (size_t)(4 * s + (t >> 1)) * 8192, lane);
      storeL(c1, ((t >> 1) & 1) ? B1 : A1);
      if ((t & 3) == 3) {
        f32x4 c2 = mfma_core<8, false>(&A1[bl], &B1[bl], LDW,
                                       U + OFF2 + (size_t)(2 * s + (t >> 2)) * 8192, lane);
        storeL(c2, ((t >> 2) & 1) ? B2 : A2);
        if (t == 7) {
          f32x4 c3 = mfma_core<8, false>(&A2[bl], &B2[bl], LDW,
                                         U + OFF3 + (size_t)s * 8192, lane);
#pragma unroll
          for (int r = 0; r < 4; ++r)
            outG[(size_t)m * BTOT + w * 16 + g * 4 + r] = c3[r];
        }
      }
    }
  }
}

// ---------------- Levels 4-7 fused, one dispatch (exact R7 structure) ----------
// Block = one 16-b tile (256 thr / 4 waves). Wave q: L4 nodes 2q,2q+1 (ILP)
// then L5 node q; barrier; waves 0,1 do L6; barrier; wave 0 does L7.
__global__ __launch_bounds__(256) void ttn_back_kernel(
    const float* __restrict__ s1, const ushort* __restrict__ U,
    float* __restrict__ out) {
  __shared__ float T[256 * 17];
  const int tid = threadIdx.x;
  const int lane = tid & 63, w = tid >> 6;
  const int m = lane & 15, g = lane >> 4;
  const int b0 = blockIdx.x * 16;

#pragma unroll
  for (int it = 0; it < 4; ++it) {      // stage [256 rows][16 b]
    int idx = it * 256 + tid;
    int r = idx >> 2, c4 = (idx & 3) * 4;
    float4 v = *(const float4*)&s1[(size_t)r * BTOT + b0 + c4];
    T[r * 17 + c4 + 0] = v.x; T[r * 17 + c4 + 1] = v.y;
    T[r * 17 + c4 + 2] = v.z; T[r * 17 + c4 + 3] = v.w;
  }
  __syncthreads();

  const int q = w, base = 64 * q;
  f32x4 a0 = mfma_core<8, false>(&T[base * 17 + m], &T[(base + 16) * 17 + m], 17,
                                 U + OFF4 + (size_t)(2 * q) * 8192, lane);
  f32x4 a1 = mfma_core<8, false>(&T[(base + 32) * 17 + m], &T[(base + 48) * 17 + m], 17,
                                 U + OFF4 + (size_t)(2 * q + 1) * 8192, lane);
#pragma unroll
  for (int r = 0; r < 4; ++r) {
    T[(base + m) * 17 + g * 4 + r] = a0[r];
    T[(base + 32 + m) * 17 + g * 4 + r] = a1[r];
  }
  f32x4 a2 = mfma_core<8, false>(&T[base * 17 + m], &T[(base + 32) * 17 + m], 17,
                                 U + OFF5 + (size_t)q * 8192, lane);
#pragma unroll
  for (int r = 0; r < 4; ++r) T[(base + m) * 17 + g * 4 + r] = a2[r];
  __syncthreads();

  if (w < 2) {
    f32x4 a3 = mfma_core<8, false>(&T[(128 * w) * 17 + m], &T[(128 * w + 64) * 17 + m],
                                   17, U + OFF6 + (size_t)w * 8192, lane);
#pragma unroll
    for (int r = 0; r < 4; ++r) T[(128 * w + m) * 17 + g * 4 + r] = a3[r];
  }
  __syncthreads();

  if (w == 0) {
    f32x4 a4 = mfma_core<8, false>(&T[m], &T[128 * 17 + m], 17, U + OFF7, lane);
    if (m == 0) {
#pragma unroll
      for (int r = 0; r < 4; ++r) out[b0 + g * 4 + r] = a4[r];
    }
  }
}

extern "C" void kernel_launch(void* const* d_in, const int* in_sizes, int n_in,
                              void* d_out, int out_size, void* d_ws, size_t ws_size,
                              hipStream_t stream) {
  const float* x    = (const float*)d_in[0];
  const float* fmin = (const float*)d_in[1];
  const float* W0   = (const float*)d_in[2];
  const float* W1   = (const float*)d_in[3];
  const float* W2   = (const float*)d_in[4];
  const float* W3   = (const float*)d_in[5];
  const float* W4   = (const float*)d_in[6];
  const float* W5   = (const float*)d_in[7];
  const float* W6   = (const float*)d_in[8];
  const float* W7   = (const float*)d_in[9];
  float* out = (float*)d_out;

  // ws: [0,4MB) W-frags U | [4MB,+16.8MB) s1
  ushort* U = (ushort*)d_ws;
  float* s1 = (float*)((char*)d_ws + (4u << 20));

  wprep_kernel<<<255, 256, 0, stream>>>(W0, W1, W2, W3, W4, W5, W6, W7, U);
  ttn_front_kernel<<<dim3(BTOT / 32, 16), 128, 0, stream>>>(x, fmin, U, s1);
  ttn_back_kernel<<<1024, 256, 0, stream>>>(s1, U, out);
}

// Round 12
// 233.775 us; speedup vs baseline: 1.0594x; 1.0594x over previous
//
#include <hip/hip_runtime.h>
#include <math.h>

#define BTOT 16384

typedef __attribute__((ext_vector_type(8))) short s16x8;
typedef __attribute__((ext_vector_type(4))) float f32x4;
typedef __attribute__((ext_vector_type(4))) uint u32x4;
typedef __attribute__((ext_vector_type(2))) float f32x2;
typedef __attribute__((ext_vector_type(2))) uint u32x2;

// U region offsets (in ushorts). Per-node blob: [KTN*512 hi][KTN*512 lo].
#define OFF0 0u          // W0: 128 nodes x 5120
#define OFF1 655360u     // W1: 64 x 8192
#define OFF2 1179648u    // W2: 32 x 8192
#define OFF3 1441792u    // W3: 16 x 8192
#define OFF4 1572864u    // W4: 8 x 8192
#define OFF5 1638400u    // W5: 4 x 8192
#define OFF6 1671168u    // W6: 2 x 8192
#define OFF7 1687552u    // W7: 1 x 8192

__device__ __forceinline__ ushort rtn_bf16(float x) {
  uint u = __builtin_bit_cast(uint, x);
  uint r = u + 0x7fffu + ((u >> 16) & 1u);
  return (ushort)(r >> 16);
}

// ---------------- W-frag prep: LDS-staged coalesced reads ----------------------
__global__ __launch_bounds__(256) void wprep_kernel(
    const float* __restrict__ W0, const float* __restrict__ W1,
    const float* __restrict__ W2, const float* __restrict__ W3,
    const float* __restrict__ W4, const float* __restrict__ W5,
    const float* __restrict__ W6, const float* __restrict__ W7,
    ushort* __restrict__ U) {
  __shared__ float WL[4096];
  int blk = blockIdx.x;
  const float* Wsrc; ushort* dst; int ktN, din, nsrc; bool dout1 = false;
  if (blk < 128)      { Wsrc = W0 + blk * 1296;         dst = U + OFF0 + (size_t)blk * 5120;         ktN = 5; din = 9;  nsrc = 1296; }
  else if (blk < 192) { Wsrc = W1 + (blk - 128) * 4096; dst = U + OFF1 + (size_t)(blk - 128) * 8192; ktN = 8; din = 16; nsrc = 4096; }
  else if (blk < 224) { Wsrc = W2 + (blk - 192) * 4096; dst = U + OFF2 + (size_t)(blk - 192) * 8192; ktN = 8; din = 16; nsrc = 4096; }
  else if (blk < 240) { Wsrc = W3 + (blk - 224) * 4096; dst = U + OFF3 + (size_t)(blk - 224) * 8192; ktN = 8; din = 16; nsrc = 4096; }
  else if (blk < 248) { Wsrc = W4 + (blk - 240) * 4096; dst = U + OFF4 + (size_t)(blk - 240) * 8192; ktN = 8; din = 16; nsrc = 4096; }
  else if (blk < 252) { Wsrc = W5 + (blk - 248) * 4096; dst = U + OFF5 + (size_t)(blk - 248) * 8192; ktN = 8; din = 16; nsrc = 4096; }
  else if (blk < 254) { Wsrc = W6 + (blk - 252) * 4096; dst = U + OFF6 + (size_t)(blk - 252) * 8192; ktN = 8; din = 16; nsrc = 4096; }
  else                { Wsrc = W7;                      dst = U + OFF7;                              ktN = 8; din = 16; nsrc = 256; dout1 = true; }
  for (int i = threadIdx.x; i < nsrc; i += 256) WL[i] = Wsrc[i];   // coalesced
  __syncthreads();
  int entries = ktN * 512;
  for (int e = threadIdx.x; e < entries; e += 256) {
    int kt = e >> 9, l = (e >> 3) & 63, jv = e & 7;
    int k = kt * 32 + ((l >> 4) << 3) + jv;
    int i = k >> 4, j = k & 15, n = l & 15;
    float w;
    if (dout1) w = (n == 0) ? WL[i * 16 + j] : 0.f;
    else       w = (i < din && j < din) ? WL[(i * din + j) * 16 + n] : 0.f;
    uint u = __builtin_bit_cast(uint, w);
    uint h = u & 0xffff0000u;
    dst[e] = (ushort)(h >> 16);
    dst[entries + e] = rtn_bf16(w - __builtin_bit_cast(float, h));
  }
}

// ---- split + 3 MFMAs for one 16-b tile, given resident wh/wl ------------------
__device__ __forceinline__ f32x4 split3(float li, const f32x2* rf2,
                                        s16x8 wh, s16x8 wl, f32x4 acc) {
  const f32x2 li2 = {li, li};
  u32x4 hv, lv;
#pragma unroll
  for (int jp = 0; jp < 4; ++jp) {
    f32x2 p2 = li2 * rf2[jp];
    u32x2 u2 = __builtin_bit_cast(u32x2, p2);
    u32x2 hb = u2 & 0xffff0000u;
    f32x2 h2 = __builtin_bit_cast(f32x2, hb);
    f32x2 q2 = __builtin_elementwise_fma(li2, rf2[jp], -h2);
    u32x2 uq = __builtin_bit_cast(u32x2, q2);
    hv[jp] = __builtin_amdgcn_perm(u2.y, u2.x, 0x07060302u);
    lv[jp] = __builtin_amdgcn_perm(uq.y, uq.x, 0x07060302u);
  }
  s16x8 ahi = __builtin_bit_cast(s16x8, hv);
  s16x8 alo = __builtin_bit_cast(s16x8, lv);
  acc = __builtin_amdgcn_mfma_f32_16x16x32_bf16(ahi, wh, acc, 0, 0, 0);
  acc = __builtin_amdgcn_mfma_f32_16x16x32_bf16(alo, wh, acc, 0, 0, 0);
  acc = __builtin_amdgcn_mfma_f32_16x16x32_bf16(ahi, wl, acc, 0, 0, 0);
  return acc;
}

// ---------------- single-tile MFMA bilinear core (verified) --------------------
// L0M: 9-dim level-0 inputs, rows >=9 read as zero (predicated; no pad row).
template <int KTN, bool L0M>
__device__ __forceinline__ f32x4 mfma_core(const float* Lcol, const float* Rcol,
                                           const int ld, const ushort* __restrict__ Wf,
                                           int lane) {
  const int g = lane >> 4;
  const int j0 = (g & 1) * 8, gh = g >> 1;
  const float* Lg = Lcol + gh * ld;
  float lf[KTN];
#pragma unroll
  for (int i = 0; i < KTN; ++i)
    lf[i] = (L0M && (2 * i + gh > 8)) ? 0.f : Lg[2 * i * ld];
  f32x2 rf2[4];
#pragma unroll
  for (int j = 0; j < 8; ++j) {
    float v = (L0M && (j0 + j >= 9)) ? 0.f : Rcol[(j0 + j) * ld];
    rf2[j >> 1][j & 1] = v;
  }
  f32x4 acc = {0.f, 0.f, 0.f, 0.f};
  const int entries = KTN * 512;
#pragma unroll
  for (int kt = 0; kt < KTN; ++kt) {
    const s16x8 wh = *(const s16x8*)&Wf[(kt * 64 + lane) * 8];
    const s16x8 wl = *(const s16x8*)&Wf[entries + (kt * 64 + lane) * 8];
    acc = split3(lf[kt], rf2, wh, wl, acc);
  }
  return acc;
}

#define LDF 67   // front leading dim: 67 % 32 = 3 -> <=2-way LDS conflicts (free)

__device__ __forceinline__ void feats_col(float xv, float* Fb, int col) {
  float s1 = __sinf(xv), c1 = __cosf(xv);
  Fb[0 * LDF + col] = 1.f; Fb[1 * LDF + col] = s1; Fb[5 * LDF + col] = c1;
  float sk = s1, ck = c1;
#pragma unroll
  for (int k = 2; k <= 4; ++k) {
    float sn = s1 * ck + c1 * sk, cn = c1 * ck - s1 * sk;
    sk = sn; ck = cn;
    Fb[k * LDF + col] = sk; Fb[(4 + k) * LDF + col] = ck;
  }
}

// ---------------- Levels 0-3 fused, zero-barrier (R7/R10 best shape) -----------
__global__ __launch_bounds__(256, 4) void ttn_front_kernel(
    const float* __restrict__ x, const float* __restrict__ fminp,
    const ushort* __restrict__ U, float* __restrict__ s1out) {
  __shared__ float F0[9 * LDF], F1[9 * LDF];
  __shared__ float A0[16 * LDF], B0[16 * LDF];
  __shared__ float A1[16 * LDF], B1[16 * LDF];
  __shared__ float A2[16 * LDF], B2[16 * LDF];

  const int tid = threadIdx.x;
  const int lane = tid & 63, w = tid >> 6;
  const int m = lane & 15, g = lane >> 4;
  const int bl = w * 16 + m;
  const int b0 = blockIdx.x * 64;
  const int s = blockIdx.y;
  const float fmin = fminp[0];

  const float* xw = x + (size_t)(b0 + w * 16 + (lane & 15)) * 256 + s * 16;
  float* outG = s1out + (size_t)(s * 16) * BTOT + b0;

  auto storeL = [&](f32x4 a, float* Out) {
#pragma unroll
    for (int r = 0; r < 4; ++r) Out[m * LDF + w * 16 + g * 4 + r] = a[r];
  };

  for (int t = 0; t < 8; ++t) {
    if (lane < 32) {
      int side = lane >> 4;
      float xv = xw[2 * t + side] * fmin;
      feats_col(xv, side ? F1 : F0, w * 16 + (lane & 15));
    }
    f32x4 a = mfma_core<5, true>(&F0[bl], &F1[bl], LDF,
                                 U + OFF0 + (size_t)(8 * s + t) * 5120, lane);
    storeL(a, (t & 1) ? B0 : A0);
    if (t & 1) {
      f32x4 c1 = mfma_core<8, false>(&A0[bl], &B0[bl], LDF,
                                     U + OFF1 + (size_t)(4 * s + (t >> 1)) * 8192, lane);
      storeL(c1, ((t >> 1) & 1) ? B1 : A1);
      if ((t & 3) == 3) {
        f32x4 c2 = mfma_core<8, false>(&A1[bl], &B1[bl], LDF,
                                       U + OFF2 + (size_t)(2 * s + (t >> 2)) * 8192, lane);
        storeL(c2, ((t >> 2) & 1) ? B2 : A2);
        if (t == 7) {
          f32x4 c3 = mfma_core<8, false>(&A2[bl], &B2[bl], LDF,
                                         U + OFF3 + (size_t)s * 8192, lane);
#pragma unroll
          for (int r = 0; r < 4; ++r)
            outG[(size_t)m * BTOT + w * 16 + g * 4 + r] = c3[r];
        }
      }
    }
  }
}

// ---------------- Levels 4-7: tree-parallel, 8 waves / 16-b tile ---------------
// Wave v: L4 node v; barrier; waves 0-3: L5; barrier; 0-1: L6; barrier; 0: L7.
// Serial depth 4 mfma_cores (vs 8 in R7-back). LDS: T (staging, dead after L4
// reads -> reused for L5 out) + P (L4 out, dead after L5 reads -> L6 out).
__global__ __launch_bounds__(512) void ttn_back_kernel(
    const float* __restrict__ s1, const ushort* __restrict__ U,
    float* __restrict__ out) {
  __shared__ float T[256 * 17];        // 17.4 KB
  __shared__ float P[8][16 * 17];      // 8.7 KB
  const int tid = threadIdx.x;
  const int lane = tid & 63, v = tid >> 6;   // v = 0..7
  const int m = lane & 15, g = lane >> 4;
  const int b0 = blockIdx.x * 16;

  auto storeC = [&](f32x4 a, float* Buf) {
#pragma unroll
    for (int r = 0; r < 4; ++r) Buf[m * 17 + g * 4 + r] = a[r];
  };

#pragma unroll
  for (int it = 0; it < 2; ++it) {     // stage [256 rows][16 b], coalesced float4
    int idx = it * 512 + tid;          // 0..1023
    int r = idx >> 2, c4 = (idx & 3) * 4;
    float4 vv = *(const float4*)&s1[(size_t)r * BTOT + b0 + c4];
    T[r * 17 + c4 + 0] = vv.x; T[r * 17 + c4 + 1] = vv.y;
    T[r * 17 + c4 + 2] = vv.z; T[r * 17 + c4 + 3] = vv.w;
  }
  __syncthreads();

  // L4 node v: rows 32v..+15 x 32v+16..+31 -> P[v]
  {
    f32x4 a = mfma_core<8, false>(&T[(32 * v) * 17 + m], &T[(32 * v + 16) * 17 + m],
                                  17, U + OFF4 + (size_t)v * 8192, lane);
    storeC(a, P[v]);
  }
  __syncthreads();

  if (v < 4) {  // L5 node v: P[2v] x P[2v+1] -> T region v (T dead)
    f32x4 a = mfma_core<8, false>(&P[2 * v][m], &P[2 * v + 1][m], 17,
                                  U + OFF5 + (size_t)v * 8192, lane);
    storeC(a, &T[v * 16 * 17]);
  }
  __syncthreads();

  if (v < 2) {  // L6 node v: Tq[2v] x Tq[2v+1] -> P[v] (P dead)
    f32x4 a = mfma_core<8, false>(&T[(2 * v) * 16 * 17 + m],
                                  &T[(2 * v + 1) * 16 * 17 + m], 17,
                                  U + OFF6 + (size_t)v * 8192, lane);
    storeC(a, P[v]);
  }
  __syncthreads();

  if (v == 0) { // L7: P[0] x P[1]; W7-frag nonzero only in d=0 column
    f32x4 a = mfma_core<8, false>(&P[0][m], &P[1][m], 17, U + OFF7, lane);
    if (m == 0) {
#pragma unroll
      for (int r = 0; r < 4; ++r) out[b0 + g * 4 + r] = a[r];
    }
  }
}

extern "C" void kernel_launch(void* const* d_in, const int* in_sizes, int n_in,
                              void* d_out, int out_size, void* d_ws, size_t ws_size,
                              hipStream_t stream) {
  const float* x    = (const float*)d_in[0];
  const float* fmin = (const float*)d_in[1];
  const float* W0   = (const float*)d_in[2];
  const float* W1   = (const float*)d_in[3];
  const float* W2   = (const float*)d_in[4];
  const float* W3   = (const float*)d_in[5];
  const float* W4   = (const float*)d_in[6];
  const float* W5   = (const float*)d_in[7];
  const float* W6   = (const float*)d_in[8];
  const float* W7   = (const float*)d_in[9];
  float* out = (float*)d_out;

  // ws: [0,4MB) W-frags U | [4MB,+16.8MB) s1
  ushort* U = (ushort*)d_ws;
  float* s1 = (float*)((char*)d_ws + (4u << 20));

  wprep_kernel<<<255, 256, 0, stream>>>(W0, W1, W2, W3, W4, W5, W6, W7, U);
  ttn_front_kernel<<<dim3(256, 16), 256, 0, stream>>>(x, fmin, U, s1);
  ttn_back_kernel<<<1024, 512, 0, stream>>>(s1, U, out);
}